// Round 10
// baseline (748.662 us; speedup 1.0000x reference)
//
#include <hip/hip_runtime.h>
#include <math.h>

#define N_NODES 100000
#define FIN     512
#define H1H     8
#define C1C     8
#define HC1     64
#define NCLS    40
#define NEG_SLOPE 0.2f

// CSR bucketing: 256 dst-nodes per bucket (R2 config, best known)
#define NPB   256
#define NBUK  391          // ceil(100000/256)
#define EPB   4096         // edges per block in bucket count/fill

// ---------------- Layer-1 GEMM + fused attention dots (exact R2 version) ----
#define TM 128
#define TN 64
#define BK 16
#define XS_LD 132

__global__ __launch_bounds__(256) void k_gemm1(const float* __restrict__ x,
                                               const float* __restrict__ W1,
                                               const float* __restrict__ att_src,
                                               const float* __restrict__ att_dst,
                                               float* __restrict__ h1,
                                               float* __restrict__ a_src,
                                               float* __restrict__ a_dst) {
    __shared__ float xs[2][BK][XS_LD];
    __shared__ float ws[2][BK][TN];
    const int tx = threadIdx.x;
    const int row_base = blockIdx.x * TM;
    const int cg = (tx & 15) << 2;
    const int rg = (tx >> 4) << 3;

    float4 xr4[2];
    float4 wr4;

    auto load_regs = [&](int k0) {
#pragma unroll
        for (int i = 0; i < 2; i++) {
            const int f  = tx + 256 * i;     // 512 float4 = 128 rows x 4
            const int r  = f >> 2;
            const int kq = (f & 3) << 2;
            const int gr = row_base + r;
            xr4[i] = (gr < N_NODES) ? *(const float4*)(x + (size_t)gr * FIN + k0 + kq)
                                    : make_float4(0.f, 0.f, 0.f, 0.f);
        }
        {
            const int kk = tx >> 4;          // 256 float4 = 16 rows x 16
            const int c4 = (tx & 15) << 2;
            wr4 = *(const float4*)(W1 + (size_t)(k0 + kk) * TN + c4);
        }
    };
    auto store_lds = [&](int buf) {
#pragma unroll
        for (int i = 0; i < 2; i++) {
            const int f  = tx + 256 * i;
            const int r  = f >> 2;
            const int kq = (f & 3) << 2;
            xs[buf][kq + 0][r] = xr4[i].x;
            xs[buf][kq + 1][r] = xr4[i].y;
            xs[buf][kq + 2][r] = xr4[i].z;
            xs[buf][kq + 3][r] = xr4[i].w;
        }
        {
            const int kk = tx >> 4;
            const int c4 = (tx & 15) << 2;
            *(float4*)&ws[buf][kk][c4] = wr4;
        }
    };

    float acc[8][4];
#pragma unroll
    for (int i = 0; i < 8; i++)
#pragma unroll
        for (int j = 0; j < 4; j++) acc[i][j] = 0.f;

    load_regs(0);
    store_lds(0);
    __syncthreads();

    int buf = 0;
    for (int k0 = 0; k0 < FIN; k0 += BK, buf ^= 1) {
        const bool more = (k0 + BK < FIN);
        if (more) load_regs(k0 + BK);
#pragma unroll
        for (int k = 0; k < BK; k++) {
            const float4 xa = *(const float4*)&xs[buf][k][rg];
            const float4 xb = *(const float4*)&xs[buf][k][rg + 4];
            const float4 wv = *(const float4*)&ws[buf][k][cg];
            const float xr[8] = {xa.x, xa.y, xa.z, xa.w, xb.x, xb.y, xb.z, xb.w};
#pragma unroll
            for (int i = 0; i < 8; i++) {
                acc[i][0] = fmaf(xr[i], wv.x, acc[i][0]);
                acc[i][1] = fmaf(xr[i], wv.y, acc[i][1]);
                acc[i][2] = fmaf(xr[i], wv.z, acc[i][2]);
                acc[i][3] = fmaf(xr[i], wv.w, acc[i][3]);
            }
        }
        if (more) {
            store_lds(buf ^ 1);
            __syncthreads();
        }
    }

    // epilogue: store h1 + fused attention dots (cols cg..cg+3 are half of
    // head cg>>3; partner lane tx^1 holds the other half)
    const float4 asv = *(const float4*)(att_src + cg);
    const float4 adv = *(const float4*)(att_dst + cg);
    const int head = cg >> 3;
#pragma unroll
    for (int i = 0; i < 8; i++) {
        const int gr = row_base + rg + i;
        if (gr < N_NODES)
            *(float4*)(h1 + (size_t)gr * HC1 + cg) =
                make_float4(acc[i][0], acc[i][1], acc[i][2], acc[i][3]);
        float ps = acc[i][0] * asv.x + acc[i][1] * asv.y + acc[i][2] * asv.z + acc[i][3] * asv.w;
        float pd = acc[i][0] * adv.x + acc[i][1] * adv.y + acc[i][2] * adv.z + acc[i][3] * adv.w;
        ps += __shfl_xor(ps, 1, 64);
        pd += __shfl_xor(pd, 1, 64);
        if (!(tx & 1) && gr < N_NODES) {
            a_src[gr * H1H + head] = ps;
            a_dst[gr * H1H + head] = pd;
        }
    }
}

// ---------------- CSR build, bucketed (R2 config) ----------------
__global__ __launch_bounds__(256) void k_bcnt(const int* __restrict__ dst, int E,
                                              int* __restrict__ gcnt) {
    __shared__ int lcnt[NBUK];
    for (int i = threadIdx.x; i < NBUK; i += 256) lcnt[i] = 0;
    __syncthreads();
    const int e0 = blockIdx.x * EPB;
#pragma unroll
    for (int i = 0; i < EPB / 256; i++) {
        const int e = e0 + i * 256 + threadIdx.x;
        if (e < E) atomicAdd(&lcnt[dst[e] >> 8], 1);
    }
    __syncthreads();
    for (int i = threadIdx.x; i < NBUK; i += 256)
        if (lcnt[i]) atomicAdd(&gcnt[i], lcnt[i]);
}

__global__ __launch_bounds__(512) void k_bscan(const int* __restrict__ gcnt,
                                               int* __restrict__ gbase,
                                               int* __restrict__ gcur, int E) {
    __shared__ int sm[512];
    const int t = threadIdx.x;
    const int v = (t < NBUK) ? gcnt[t] : 0;
    sm[t] = v;
    __syncthreads();
    for (int off = 1; off < 512; off <<= 1) {
        const int u = (t >= off) ? sm[t - off] : 0;
        __syncthreads();
        sm[t] += u;
        __syncthreads();
    }
    if (t < NBUK) {
        const int b = sm[t] - v;
        gbase[t] = b;
        gcur[t]  = b;
    }
    if (t == 0) gbase[NBUK] = E;
}

__global__ __launch_bounds__(256) void k_bfill(const int* __restrict__ src,
                                               const int* __restrict__ dst, int E,
                                               int* __restrict__ gcur,
                                               int2* __restrict__ pairs) {
    __shared__ int lcnt[NBUK];
    __shared__ int lbase[NBUK];
    for (int i = threadIdx.x; i < NBUK; i += 256) lcnt[i] = 0;
    __syncthreads();
    const int e0 = blockIdx.x * EPB;
#pragma unroll
    for (int i = 0; i < EPB / 256; i++) {
        const int e = e0 + i * 256 + threadIdx.x;
        if (e < E) atomicAdd(&lcnt[dst[e] >> 8], 1);
    }
    __syncthreads();
    for (int i = threadIdx.x; i < NBUK; i += 256)
        lbase[i] = lcnt[i] ? atomicAdd(&gcur[i], lcnt[i]) : 0;
    __syncthreads();
#pragma unroll
    for (int i = 0; i < EPB / 256; i++) {
        const int e = e0 + i * 256 + threadIdx.x;
        if (e < E) {
            const int d = dst[e];
            const int pos = atomicAdd(&lbase[d >> 8], 1);
            pairs[pos] = make_int2(src[e], d);
        }
    }
}

__global__ __launch_bounds__(256) void k_bscatter(const int2* __restrict__ pairs,
                                                  const int* __restrict__ gbase,
                                                  int* __restrict__ offs,
                                                  int* __restrict__ srcsort, int E) {
    __shared__ int ldeg[NPB];
    __shared__ int ltmp[NPB];
    __shared__ int lcur[NPB];
    const int b = blockIdx.x;
    const int tx = threadIdx.x;
    const int node0 = b << 8;
    const int pbeg = gbase[b];
    const int cnt  = gbase[b + 1] - pbeg;

    ldeg[tx] = 0;
    __syncthreads();
    for (int i = tx; i < cnt; i += 256)
        atomicAdd(&ldeg[pairs[pbeg + i].y - node0], 1);
    __syncthreads();
    const int v = ldeg[tx];
    ltmp[tx] = v;
    __syncthreads();
    for (int off = 1; off < 256; off <<= 1) {
        const int u = (tx >= off) ? ltmp[tx - off] : 0;
        __syncthreads();
        ltmp[tx] += u;
        __syncthreads();
    }
    const int mypos = pbeg + ltmp[tx] - v;
    if (node0 + tx < N_NODES) offs[node0 + tx] = mypos;
    lcur[tx] = mypos;
    if (b == NBUK - 1 && tx == 0) offs[N_NODES] = E;
    __syncthreads();
    for (int i = tx; i < cnt; i += 256) {
        const int2 p = pairs[pbeg + i];
        const int pos = atomicAdd(&lcur[p.y - node0], 1);
        srcsort[pos] = p.x;
    }
}

// ---------------- Layer-1: single-pass batched online softmax + aggregate ----------------
__global__ __launch_bounds__(256) void k_agg1(const float* __restrict__ h1,
                                              const float* __restrict__ a_src,
                                              const float* __restrict__ a_dst,
                                              const int* __restrict__ offs,
                                              const int* __restrict__ srcsort,
                                              const float* __restrict__ b1,
                                              float* __restrict__ h1e) {
    const int n = blockIdx.x * 4 + (threadIdx.x >> 6);
    if (n >= N_NODES) return;
    const int lane = threadIdx.x & 63;
    const int hh   = lane >> 3;
    const float adn = a_dst[n * H1H + hh];
    const int beg = offs[n], end = offs[n + 1];

    float e0 = a_src[n * H1H + hh] + adn;
    e0 = e0 > 0.f ? e0 : NEG_SLOPE * e0;
    float m = e0;
    float denom = 1.f;
    float acc = h1[(size_t)n * HC1 + lane];

    int j = beg;
    for (; j + 8 <= end; j += 8) {
        int s[8];
#pragma unroll
        for (int t = 0; t < 8; t++) s[t] = srcsort[j + t];
        float q[8], g[8];
#pragma unroll
        for (int t = 0; t < 8; t++) q[t] = a_src[s[t] * H1H + hh];
#pragma unroll
        for (int t = 0; t < 8; t++) g[t] = h1[(size_t)s[t] * HC1 + lane];
        float f[8];
#pragma unroll
        for (int t = 0; t < 8; t++) {
            const float e = q[t] + adn;
            f[t] = e > 0.f ? e : NEG_SLOPE * e;
        }
        const float cm = fmaxf(fmaxf(fmaxf(f[0], f[1]), fmaxf(f[2], f[3])),
                               fmaxf(fmaxf(f[4], f[5]), fmaxf(f[6], f[7])));
        const float nm = fmaxf(m, cm);
        const float sc = __expf(m - nm);
        float w[8];
#pragma unroll
        for (int t = 0; t < 8; t++) w[t] = __expf(f[t] - nm);
        const float wsum = ((w[0] + w[1]) + (w[2] + w[3])) + ((w[4] + w[5]) + (w[6] + w[7]));
        const float wg = fmaf(w[0], g[0], fmaf(w[1], g[1], fmaf(w[2], g[2], fmaf(w[3], g[3],
                         fmaf(w[4], g[4], fmaf(w[5], g[5], fmaf(w[6], g[6], w[7] * g[7])))))));
        denom = fmaf(denom, sc, wsum);
        acc = fmaf(acc, sc, wg);
        m = nm;
    }
    for (; j + 4 <= end; j += 4) {
        const int s0 = srcsort[j], s1 = srcsort[j + 1];
        const int s2 = srcsort[j + 2], s3 = srcsort[j + 3];
        const float q0 = a_src[s0 * H1H + hh], q1 = a_src[s1 * H1H + hh];
        const float q2 = a_src[s2 * H1H + hh], q3 = a_src[s3 * H1H + hh];
        const float g0 = h1[(size_t)s0 * HC1 + lane];
        const float g1 = h1[(size_t)s1 * HC1 + lane];
        const float g2 = h1[(size_t)s2 * HC1 + lane];
        const float g3 = h1[(size_t)s3 * HC1 + lane];
        float f0 = q0 + adn; f0 = f0 > 0.f ? f0 : NEG_SLOPE * f0;
        float f1 = q1 + adn; f1 = f1 > 0.f ? f1 : NEG_SLOPE * f1;
        float f2 = q2 + adn; f2 = f2 > 0.f ? f2 : NEG_SLOPE * f2;
        float f3 = q3 + adn; f3 = f3 > 0.f ? f3 : NEG_SLOPE * f3;
        const float nm = fmaxf(m, fmaxf(fmaxf(f0, f1), fmaxf(f2, f3)));
        const float sc = __expf(m - nm);
        const float w0 = __expf(f0 - nm), w1 = __expf(f1 - nm);
        const float w2 = __expf(f2 - nm), w3 = __expf(f3 - nm);
        denom = fmaf(denom, sc, (w0 + w1) + (w2 + w3));
        acc = fmaf(acc, sc, fmaf(w0, g0, fmaf(w1, g1, fmaf(w2, g2, w3 * g3))));
        m = nm;
    }
    for (; j < end; j++) {
        const int s = srcsort[j];
        float e = a_src[s * H1H + hh] + adn;
        e = e > 0.f ? e : NEG_SLOPE * e;
        const float g = h1[(size_t)s * HC1 + lane];
        const float nm = fmaxf(m, e);
        const float sc = __expf(m - nm);
        const float w = __expf(e - nm);
        denom = fmaf(denom, sc, w);
        acc = fmaf(acc, sc, w * g);
        m = nm;
    }
    float v = acc / denom + b1[lane];
    h1e[(size_t)n * HC1 + lane] = v > 0.f ? v : (__expf(v) - 1.f);
}

// ---------------- Layer-2 GEMM (64->40), LDS-tiled, + fused attention dots ----
#define TM2 128
__global__ __launch_bounds__(256) void k_gemm2(const float* __restrict__ h1e,
                                               const float* __restrict__ W2,
                                               const float* __restrict__ att_src2,
                                               const float* __restrict__ att_dst2,
                                               float* __restrict__ h2,
                                               float* __restrict__ a_src2,
                                               float* __restrict__ a_dst2) {
    __shared__ float hs[32][65][4];   // [node_group][k(+pad)][node_in_group]
    __shared__ float w2t[NCLS][68];   // transposed W2, padded
    __shared__ float asv[NCLS], adv[NCLS];
    const int tx = threadIdx.x;
    const int node0 = blockIdx.x * TM2;

    for (int f = tx; f < HC1 * NCLS; f += 256) {
        const int k = f / NCLS, c = f - k * NCLS;
        w2t[c][k] = W2[f];
    }
    if (tx < NCLS) {
        asv[tx] = att_src2[tx];
        adv[tx] = att_dst2[tx];
    }
#pragma unroll
    for (int i = 0; i < 8; i++) {
        const int f  = tx + 256 * i;      // 2048 float4 = 128 rows x 16
        const int n  = f >> 4;
        const int k4 = (f & 15) << 2;
        const int gn = node0 + n;
        const float4 v = (gn < N_NODES) ? *(const float4*)(h1e + (size_t)gn * HC1 + k4)
                                        : make_float4(0.f, 0.f, 0.f, 0.f);
        const int ng = n >> 2, ni = n & 3;
        hs[ng][k4 + 0][ni] = v.x;
        hs[ng][k4 + 1][ni] = v.y;
        hs[ng][k4 + 2][ni] = v.z;
        hs[ng][k4 + 3][ni] = v.w;
    }
    __syncthreads();

    const int ng = tx >> 3;          // 0..31 -> nodes ng*4..ng*4+3
    const int cg = tx & 7;           // 0..7  -> classes cg*5..cg*5+4
    const int c0 = cg * 5;

    float acc[4][5];
#pragma unroll
    for (int i = 0; i < 4; i++)
#pragma unroll
        for (int j = 0; j < 5; j++) acc[i][j] = 0.f;

    for (int k = 0; k < HC1; k += 4) {
        float4 hv[4];
#pragma unroll
        for (int t = 0; t < 4; t++) hv[t] = *(const float4*)&hs[ng][k + t][0];
#pragma unroll
        for (int j = 0; j < 5; j++) {
            const float4 wv = *(const float4*)&w2t[c0 + j][k];
            acc[0][j] = fmaf(hv[0].x, wv.x, fmaf(hv[1].x, wv.y, fmaf(hv[2].x, wv.z, fmaf(hv[3].x, wv.w, acc[0][j]))));
            acc[1][j] = fmaf(hv[0].y, wv.x, fmaf(hv[1].y, wv.y, fmaf(hv[2].y, wv.z, fmaf(hv[3].y, wv.w, acc[1][j]))));
            acc[2][j] = fmaf(hv[0].z, wv.x, fmaf(hv[1].z, wv.y, fmaf(hv[2].z, wv.z, fmaf(hv[3].z, wv.w, acc[2][j]))));
            acc[3][j] = fmaf(hv[0].w, wv.x, fmaf(hv[1].w, wv.y, fmaf(hv[2].w, wv.z, fmaf(hv[3].w, wv.w, acc[3][j]))));
        }
    }

    // store h2 + fused att dots (reduce partials over the 8 cg lanes)
    float ps[4], pd[4];
#pragma unroll
    for (int i = 0; i < 4; i++) {
        const int gn = node0 + ng * 4 + i;
        float s = 0.f, d = 0.f;
#pragma unroll
        for (int j = 0; j < 5; j++) {
            s = fmaf(acc[i][j], asv[c0 + j], s);
            d = fmaf(acc[i][j], adv[c0 + j], d);
        }
        ps[i] = s;
        pd[i] = d;
        if (gn < N_NODES) {
#pragma unroll
            for (int j = 0; j < 5; j++)
                h2[(size_t)gn * NCLS + c0 + j] = acc[i][j];
        }
    }
#pragma unroll
    for (int off = 1; off < 8; off <<= 1) {
#pragma unroll
        for (int i = 0; i < 4; i++) {
            ps[i] += __shfl_xor(ps[i], off, 64);
            pd[i] += __shfl_xor(pd[i], off, 64);
        }
    }
    if (cg == 0) {
#pragma unroll
        for (int i = 0; i < 4; i++) {
            const int gn = node0 + ng * 4 + i;
            if (gn < N_NODES) {
                a_src2[gn] = ps[i];
                a_dst2[gn] = pd[i];
            }
        }
    }
}

// ---------------- Layer-2: single-pass online softmax-aggregate + class softmax ----------------
__global__ __launch_bounds__(256) void k_agg2(const float* __restrict__ h2,
                                              const float* __restrict__ a_src,
                                              const float* __restrict__ a_dst,
                                              const int* __restrict__ offs,
                                              const int* __restrict__ srcsort,
                                              const float* __restrict__ b2,
                                              float* __restrict__ out) {
    const int n = blockIdx.x * 4 + (threadIdx.x >> 6);
    if (n >= N_NODES) return;
    const int lane = threadIdx.x & 63;
    const float adn = a_dst[n];
    const int beg = offs[n], end = offs[n + 1];

    float e0 = a_src[n] + adn;
    e0 = e0 > 0.f ? e0 : NEG_SLOPE * e0;
    float m = e0;
    float denom = 1.f;
    float acc = (lane < NCLS) ? h2[(size_t)n * NCLS + lane] : 0.f;

    int j = beg;
    for (; j + 8 <= end; j += 8) {
        int s[8];
#pragma unroll
        for (int t = 0; t < 8; t++) s[t] = srcsort[j + t];
        float q[8], g[8];
#pragma unroll
        for (int t = 0; t < 8; t++) q[t] = a_src[s[t]];
#pragma unroll
        for (int t = 0; t < 8; t++)
            g[t] = (lane < NCLS) ? h2[(size_t)s[t] * NCLS + lane] : 0.f;
        float f[8];
#pragma unroll
        for (int t = 0; t < 8; t++) {
            const float e = q[t] + adn;
            f[t] = e > 0.f ? e : NEG_SLOPE * e;
        }
        const float cm = fmaxf(fmaxf(fmaxf(f[0], f[1]), fmaxf(f[2], f[3])),
                               fmaxf(fmaxf(f[4], f[5]), fmaxf(f[6], f[7])));
        const float nm = fmaxf(m, cm);
        const float sc = __expf(m - nm);
        float w[8];
#pragma unroll
        for (int t = 0; t < 8; t++) w[t] = __expf(f[t] - nm);
        const float wsum = ((w[0] + w[1]) + (w[2] + w[3])) + ((w[4] + w[5]) + (w[6] + w[7]));
        const float wg = fmaf(w[0], g[0], fmaf(w[1], g[1], fmaf(w[2], g[2], fmaf(w[3], g[3],
                         fmaf(w[4], g[4], fmaf(w[5], g[5], fmaf(w[6], g[6], w[7] * g[7])))))));
        denom = fmaf(denom, sc, wsum);
        acc = fmaf(acc, sc, wg);
        m = nm;
    }
    for (; j + 4 <= end; j += 4) {
        const int s0 = srcsort[j], s1 = srcsort[j + 1];
        const int s2 = srcsort[j + 2], s3 = srcsort[j + 3];
        const float q0 = a_src[s0], q1 = a_src[s1];
        const float q2 = a_src[s2], q3 = a_src[s3];
        float g0 = 0.f, g1 = 0.f, g2 = 0.f, g3 = 0.f;
        if (lane < NCLS) {
            g0 = h2[(size_t)s0 * NCLS + lane];
            g1 = h2[(size_t)s1 * NCLS + lane];
            g2 = h2[(size_t)s2 * NCLS + lane];
            g3 = h2[(size_t)s3 * NCLS + lane];
        }
        float f0 = q0 + adn; f0 = f0 > 0.f ? f0 : NEG_SLOPE * f0;
        float f1 = q1 + adn; f1 = f1 > 0.f ? f1 : NEG_SLOPE * f1;
        float f2 = q2 + adn; f2 = f2 > 0.f ? f2 : NEG_SLOPE * f2;
        float f3 = q3 + adn; f3 = f3 > 0.f ? f3 : NEG_SLOPE * f3;
        const float nm = fmaxf(m, fmaxf(fmaxf(f0, f1), fmaxf(f2, f3)));
        const float sc = __expf(m - nm);
        const float w0 = __expf(f0 - nm), w1 = __expf(f1 - nm);
        const float w2 = __expf(f2 - nm), w3 = __expf(f3 - nm);
        denom = fmaf(denom, sc, (w0 + w1) + (w2 + w3));
        acc = fmaf(acc, sc, fmaf(w0, g0, fmaf(w1, g1, fmaf(w2, g2, w3 * g3))));
        m = nm;
    }
    for (; j < end; j++) {
        const int s = srcsort[j];
        float e = a_src[s] + adn;
        e = e > 0.f ? e : NEG_SLOPE * e;
        const float g = (lane < NCLS) ? h2[(size_t)s * NCLS + lane] : 0.f;
        const float nm = fmaxf(m, e);
        const float sc = __expf(m - nm);
        const float w = __expf(e - nm);
        denom = fmaf(denom, sc, w);
        acc = fmaf(acc, sc, w * g);
        m = nm;
    }
    float o = (lane < NCLS) ? (acc / denom + b2[lane]) : -INFINITY;
    float mx = o;
#pragma unroll
    for (int off = 32; off; off >>= 1) mx = fmaxf(mx, __shfl_xor(mx, off, 64));
    const float ex = (lane < NCLS) ? __expf(o - mx) : 0.f;
    float sm = ex;
#pragma unroll
    for (int off = 32; off; off >>= 1) sm += __shfl_xor(sm, off, 64);
    if (lane < NCLS) out[(size_t)n * NCLS + lane] = ex / sm;
}

// ---------------- launcher ----------------
// R10 ATTRIBUTION ROUND: exact R2 pipeline, but k_agg1 and k_agg2 launched
// TWICE each (idempotent). dur delta vs 587.3us = agg1+agg2 total cost.
extern "C" void kernel_launch(void* const* d_in, const int* in_sizes, int n_in,
                              void* d_out, int out_size, void* d_ws, size_t ws_size,
                              hipStream_t stream) {
    const float* x   = (const float*)d_in[0];
    const int*   ei  = (const int*)d_in[1];
    const float* W1v = (const float*)d_in[2];
    const float* as1 = (const float*)d_in[3];
    const float* ad1 = (const float*)d_in[4];
    const float* b1  = (const float*)d_in[5];
    const float* W2v = (const float*)d_in[6];
    const float* as2 = (const float*)d_in[7];
    const float* ad2 = (const float*)d_in[8];
    const float* b2  = (const float*)d_in[9];
    const int E = in_sizes[1] / 2;
    const int* esrc = ei;
    const int* edst = ei + E;

    char* wp = (char*)d_ws;
    auto alloc = [&](size_t bytes) {
        char* p = wp;
        wp += (bytes + 255) & ~(size_t)255;
        return p;
    };
    float* h1     = (float*)alloc((size_t)N_NODES * HC1 * 4);
    float* h1e    = (float*)alloc((size_t)N_NODES * HC1 * 4);
    float* a_src1 = (float*)alloc((size_t)N_NODES * H1H * 4);
    float* a_dst1 = (float*)alloc((size_t)N_NODES * H1H * 4);
    float* a_src2 = (float*)alloc((size_t)N_NODES * 4);
    float* a_dst2 = (float*)alloc((size_t)N_NODES * 4);
    int*   offs   = (int*)alloc((size_t)(N_NODES + 1) * 4);
    int*   gcnt   = (int*)alloc((size_t)NBUK * 4);
    int*   gbase  = (int*)alloc((size_t)(NBUK + 1) * 4);
    int*   gcur   = (int*)alloc((size_t)NBUK * 4);
    int*   srcsort= (int*)alloc((size_t)E * 4);
    int2*  pairs  = (int2*)alloc((size_t)E * 8);
    float* h2     = h1;  // h1 dead after k_agg1 (both runs); reuse for h2

    hipMemsetAsync(gcnt, 0, (size_t)NBUK * 4, stream);

    const int NEB = (E + EPB - 1) / EPB;
    k_gemm1<<<(N_NODES + TM - 1) / TM, 256, 0, stream>>>(x, W1v, as1, ad1, h1, a_src1, a_dst1);
    k_bcnt<<<NEB, 256, 0, stream>>>(edst, E, gcnt);
    k_bscan<<<1, 512, 0, stream>>>(gcnt, gbase, gcur, E);
    k_bfill<<<NEB, 256, 0, stream>>>(esrc, edst, E, gcur, pairs);
    k_bscatter<<<NBUK, 256, 0, stream>>>(pairs, gbase, offs, srcsort, E);
    k_agg1<<<(N_NODES + 3) / 4, 256, 0, stream>>>(h1, a_src1, a_dst1, offs, srcsort, b1, h1e);
    k_agg1<<<(N_NODES + 3) / 4, 256, 0, stream>>>(h1, a_src1, a_dst1, offs, srcsort, b1, h1e);  // dup (attribution)
    k_gemm2<<<(N_NODES + TM2 - 1) / TM2, 256, 0, stream>>>(h1e, W2v, as2, ad2, h2, a_src2, a_dst2);
    k_agg2<<<(N_NODES + 3) / 4, 256, 0, stream>>>(h2, a_src2, a_dst2, offs, srcsort, b2, (float*)d_out);
    k_agg2<<<(N_NODES + 3) / 4, 256, 0, stream>>>(h2, a_src2, a_dst2, offs, srcsort, b2, (float*)d_out);  // dup (attribution)
}

// Round 11
// 580.336 us; speedup vs baseline: 1.2900x; 1.2900x over previous
//
#include <hip/hip_runtime.h>
#include <math.h>

#define N_NODES 100000
#define FIN     512
#define H1H     8
#define C1C     8
#define HC1     64
#define NCLS    40
#define NEG_SLOPE 0.2f

// CSR bucketing: 256 dst-nodes per bucket, bucket-strided pairs regions (R11).
// CAP = mean(4096) + 16 sigma(64) -> overflow prob ~1e-30, deterministic.
#define NPB   256
#define NBUK  391          // ceil(100000/256)
#define EPB   2048         // edges per block in fused fill (782 blocks, 3/CU)
#define CAP   5120         // per-bucket pairs capacity

// ---------------- Layer-1 GEMM + fused attention dots (exact R2 version) ----
#define TM 128
#define TN 64
#define BK 16
#define XS_LD 132

__global__ __launch_bounds__(256) void k_gemm1(const float* __restrict__ x,
                                               const float* __restrict__ W1,
                                               const float* __restrict__ att_src,
                                               const float* __restrict__ att_dst,
                                               float* __restrict__ h1,
                                               float* __restrict__ a_src,
                                               float* __restrict__ a_dst) {
    __shared__ float xs[2][BK][XS_LD];
    __shared__ float ws[2][BK][TN];
    const int tx = threadIdx.x;
    const int row_base = blockIdx.x * TM;
    const int cg = (tx & 15) << 2;
    const int rg = (tx >> 4) << 3;

    float4 xr4[2];
    float4 wr4;

    auto load_regs = [&](int k0) {
#pragma unroll
        for (int i = 0; i < 2; i++) {
            const int f  = tx + 256 * i;     // 512 float4 = 128 rows x 4
            const int r  = f >> 2;
            const int kq = (f & 3) << 2;
            const int gr = row_base + r;
            xr4[i] = (gr < N_NODES) ? *(const float4*)(x + (size_t)gr * FIN + k0 + kq)
                                    : make_float4(0.f, 0.f, 0.f, 0.f);
        }
        {
            const int kk = tx >> 4;          // 256 float4 = 16 rows x 16
            const int c4 = (tx & 15) << 2;
            wr4 = *(const float4*)(W1 + (size_t)(k0 + kk) * TN + c4);
        }
    };
    auto store_lds = [&](int buf) {
#pragma unroll
        for (int i = 0; i < 2; i++) {
            const int f  = tx + 256 * i;
            const int r  = f >> 2;
            const int kq = (f & 3) << 2;
            xs[buf][kq + 0][r] = xr4[i].x;
            xs[buf][kq + 1][r] = xr4[i].y;
            xs[buf][kq + 2][r] = xr4[i].z;
            xs[buf][kq + 3][r] = xr4[i].w;
        }
        {
            const int kk = tx >> 4;
            const int c4 = (tx & 15) << 2;
            *(float4*)&ws[buf][kk][c4] = wr4;
        }
    };

    float acc[8][4];
#pragma unroll
    for (int i = 0; i < 8; i++)
#pragma unroll
        for (int j = 0; j < 4; j++) acc[i][j] = 0.f;

    load_regs(0);
    store_lds(0);
    __syncthreads();

    int buf = 0;
    for (int k0 = 0; k0 < FIN; k0 += BK, buf ^= 1) {
        const bool more = (k0 + BK < FIN);
        if (more) load_regs(k0 + BK);
#pragma unroll
        for (int k = 0; k < BK; k++) {
            const float4 xa = *(const float4*)&xs[buf][k][rg];
            const float4 xb = *(const float4*)&xs[buf][k][rg + 4];
            const float4 wv = *(const float4*)&ws[buf][k][cg];
            const float xr[8] = {xa.x, xa.y, xa.z, xa.w, xb.x, xb.y, xb.z, xb.w};
#pragma unroll
            for (int i = 0; i < 8; i++) {
                acc[i][0] = fmaf(xr[i], wv.x, acc[i][0]);
                acc[i][1] = fmaf(xr[i], wv.y, acc[i][1]);
                acc[i][2] = fmaf(xr[i], wv.z, acc[i][2]);
                acc[i][3] = fmaf(xr[i], wv.w, acc[i][3]);
            }
        }
        if (more) {
            store_lds(buf ^ 1);
            __syncthreads();
        }
    }

    // epilogue: store h1 + fused attention dots (cols cg..cg+3 are half of
    // head cg>>3; partner lane tx^1 holds the other half)
    const float4 asv = *(const float4*)(att_src + cg);
    const float4 adv = *(const float4*)(att_dst + cg);
    const int head = cg >> 3;
#pragma unroll
    for (int i = 0; i < 8; i++) {
        const int gr = row_base + rg + i;
        if (gr < N_NODES)
            *(float4*)(h1 + (size_t)gr * HC1 + cg) =
                make_float4(acc[i][0], acc[i][1], acc[i][2], acc[i][3]);
        float ps = acc[i][0] * asv.x + acc[i][1] * asv.y + acc[i][2] * asv.z + acc[i][3] * asv.w;
        float pd = acc[i][0] * adv.x + acc[i][1] * adv.y + acc[i][2] * adv.z + acc[i][3] * adv.w;
        ps += __shfl_xor(ps, 1, 64);
        pd += __shfl_xor(pd, 1, 64);
        if (!(tx & 1) && gr < N_NODES) {
            a_src[gr * H1H + head] = ps;
            a_dst[gr * H1H + head] = pd;
        }
    }
}

// ---------------- CSR build (R11: fused fill, no count pre-pass) ------------
// Each bucket owns pairs[b*CAP .. b*CAP+CAP). Blocks reserve chunks with one
// global atomic per (block,bucket) from a block-local histogram. gcur ends
// holding exact bucket counts, which k_bscan turns into srcsort bases.
__global__ __launch_bounds__(256) void k_bfill(const int* __restrict__ src,
                                               const int* __restrict__ dst, int E,
                                               int* __restrict__ gcur,
                                               int2* __restrict__ pairs) {
    __shared__ int lcnt[NBUK];
    __shared__ int lbase[NBUK];
    for (int i = threadIdx.x; i < NBUK; i += 256) lcnt[i] = 0;
    __syncthreads();
    const int e0 = blockIdx.x * EPB;
#pragma unroll
    for (int i = 0; i < EPB / 256; i++) {
        const int e = e0 + i * 256 + threadIdx.x;
        if (e < E) atomicAdd(&lcnt[dst[e] >> 8], 1);
    }
    __syncthreads();
    for (int i = threadIdx.x; i < NBUK; i += 256)
        lbase[i] = lcnt[i] ? (i * CAP + atomicAdd(&gcur[i], lcnt[i])) : 0;
    __syncthreads();
#pragma unroll
    for (int i = 0; i < EPB / 256; i++) {
        const int e = e0 + i * 256 + threadIdx.x;
        if (e < E) {
            const int d = dst[e];
            const int b = d >> 8;
            const int pos = atomicAdd(&lbase[b], 1);
            if (pos < b * CAP + CAP)           // overflow guard (never fires)
                pairs[pos] = make_int2(src[e], d);
        }
    }
}

// exclusive scan of bucket counts -> srcsort bases
__global__ __launch_bounds__(512) void k_bscan(const int* __restrict__ cnts,
                                               int* __restrict__ gbase) {
    __shared__ int sm[512];
    const int t = threadIdx.x;
    const int v = (t < NBUK) ? cnts[t] : 0;
    sm[t] = v;
    __syncthreads();
    for (int off = 1; off < 512; off <<= 1) {
        const int u = (t >= off) ? sm[t - off] : 0;
        __syncthreads();
        sm[t] += u;
        __syncthreads();
    }
    if (t < NBUK) gbase[t] = sm[t] - v;
}

__global__ __launch_bounds__(256) void k_bscatter(const int2* __restrict__ pairs,
                                                  const int* __restrict__ cnts,
                                                  const int* __restrict__ gbase,
                                                  int* __restrict__ offs,
                                                  int* __restrict__ srcsort, int E) {
    __shared__ int ldeg[NPB];
    __shared__ int ltmp[NPB];
    __shared__ int lcur[NPB];
    const int b = blockIdx.x;
    const int tx = threadIdx.x;
    const int node0 = b << 8;
    const int pbeg = b * CAP;          // read base (bucket-strided region)
    const int cnt  = cnts[b];
    const int wbase = gbase[b];        // write base in srcsort/offs

    ldeg[tx] = 0;
    __syncthreads();
    for (int i = tx; i < cnt; i += 256)
        atomicAdd(&ldeg[pairs[pbeg + i].y - node0], 1);
    __syncthreads();
    const int v = ldeg[tx];
    ltmp[tx] = v;
    __syncthreads();
    for (int off = 1; off < 256; off <<= 1) {
        const int u = (tx >= off) ? ltmp[tx - off] : 0;
        __syncthreads();
        ltmp[tx] += u;
        __syncthreads();
    }
    const int mypos = wbase + ltmp[tx] - v;
    if (node0 + tx < N_NODES) offs[node0 + tx] = mypos;
    lcur[tx] = mypos;
    if (b == NBUK - 1 && tx == 0) offs[N_NODES] = E;
    __syncthreads();
    for (int i = tx; i < cnt; i += 256) {
        const int2 p = pairs[pbeg + i];
        const int pos = atomicAdd(&lcur[p.y - node0], 1);
        srcsort[pos] = p.x;
    }
}

// ---------------- Layer-1: single-pass batched online softmax + aggregate ----------------
__global__ __launch_bounds__(256) void k_agg1(const float* __restrict__ h1,
                                              const float* __restrict__ a_src,
                                              const float* __restrict__ a_dst,
                                              const int* __restrict__ offs,
                                              const int* __restrict__ srcsort,
                                              const float* __restrict__ b1,
                                              float* __restrict__ h1e) {
    const int n = blockIdx.x * 4 + (threadIdx.x >> 6);
    if (n >= N_NODES) return;
    const int lane = threadIdx.x & 63;
    const int hh   = lane >> 3;
    const float adn = a_dst[n * H1H + hh];
    const int beg = offs[n], end = offs[n + 1];

    float e0 = a_src[n * H1H + hh] + adn;
    e0 = e0 > 0.f ? e0 : NEG_SLOPE * e0;
    float m = e0;
    float denom = 1.f;
    float acc = h1[(size_t)n * HC1 + lane];

    int j = beg;
    for (; j + 8 <= end; j += 8) {
        int s[8];
#pragma unroll
        for (int t = 0; t < 8; t++) s[t] = srcsort[j + t];
        float q[8], g[8];
#pragma unroll
        for (int t = 0; t < 8; t++) q[t] = a_src[s[t] * H1H + hh];
#pragma unroll
        for (int t = 0; t < 8; t++) g[t] = h1[(size_t)s[t] * HC1 + lane];
        float f[8];
#pragma unroll
        for (int t = 0; t < 8; t++) {
            const float e = q[t] + adn;
            f[t] = e > 0.f ? e : NEG_SLOPE * e;
        }
        const float cm = fmaxf(fmaxf(fmaxf(f[0], f[1]), fmaxf(f[2], f[3])),
                               fmaxf(fmaxf(f[4], f[5]), fmaxf(f[6], f[7])));
        const float nm = fmaxf(m, cm);
        const float sc = __expf(m - nm);
        float w[8];
#pragma unroll
        for (int t = 0; t < 8; t++) w[t] = __expf(f[t] - nm);
        const float wsum = ((w[0] + w[1]) + (w[2] + w[3])) + ((w[4] + w[5]) + (w[6] + w[7]));
        const float wg = fmaf(w[0], g[0], fmaf(w[1], g[1], fmaf(w[2], g[2], fmaf(w[3], g[3],
                         fmaf(w[4], g[4], fmaf(w[5], g[5], fmaf(w[6], g[6], w[7] * g[7])))))));
        denom = fmaf(denom, sc, wsum);
        acc = fmaf(acc, sc, wg);
        m = nm;
    }
    for (; j + 4 <= end; j += 4) {
        const int s0 = srcsort[j], s1 = srcsort[j + 1];
        const int s2 = srcsort[j + 2], s3 = srcsort[j + 3];
        const float q0 = a_src[s0 * H1H + hh], q1 = a_src[s1 * H1H + hh];
        const float q2 = a_src[s2 * H1H + hh], q3 = a_src[s3 * H1H + hh];
        const float g0 = h1[(size_t)s0 * HC1 + lane];
        const float g1 = h1[(size_t)s1 * HC1 + lane];
        const float g2 = h1[(size_t)s2 * HC1 + lane];
        const float g3 = h1[(size_t)s3 * HC1 + lane];
        float f0 = q0 + adn; f0 = f0 > 0.f ? f0 : NEG_SLOPE * f0;
        float f1 = q1 + adn; f1 = f1 > 0.f ? f1 : NEG_SLOPE * f1;
        float f2 = q2 + adn; f2 = f2 > 0.f ? f2 : NEG_SLOPE * f2;
        float f3 = q3 + adn; f3 = f3 > 0.f ? f3 : NEG_SLOPE * f3;
        const float nm = fmaxf(m, fmaxf(fmaxf(f0, f1), fmaxf(f2, f3)));
        const float sc = __expf(m - nm);
        const float w0 = __expf(f0 - nm), w1 = __expf(f1 - nm);
        const float w2 = __expf(f2 - nm), w3 = __expf(f3 - nm);
        denom = fmaf(denom, sc, (w0 + w1) + (w2 + w3));
        acc = fmaf(acc, sc, fmaf(w0, g0, fmaf(w1, g1, fmaf(w2, g2, w3 * g3))));
        m = nm;
    }
    for (; j < end; j++) {
        const int s = srcsort[j];
        float e = a_src[s * H1H + hh] + adn;
        e = e > 0.f ? e : NEG_SLOPE * e;
        const float g = h1[(size_t)s * HC1 + lane];
        const float nm = fmaxf(m, e);
        const float sc = __expf(m - nm);
        const float w = __expf(e - nm);
        denom = fmaf(denom, sc, w);
        acc = fmaf(acc, sc, w * g);
        m = nm;
    }
    float v = acc / denom + b1[lane];
    h1e[(size_t)n * HC1 + lane] = v > 0.f ? v : (__expf(v) - 1.f);
}

// ---------------- Layer-2 GEMM (64->40), LDS-tiled, + fused attention dots ----
#define TM2 128
__global__ __launch_bounds__(256) void k_gemm2(const float* __restrict__ h1e,
                                               const float* __restrict__ W2,
                                               const float* __restrict__ att_src2,
                                               const float* __restrict__ att_dst2,
                                               float* __restrict__ h2,
                                               float* __restrict__ a_src2,
                                               float* __restrict__ a_dst2) {
    __shared__ float hs[32][65][4];   // [node_group][k(+pad)][node_in_group]
    __shared__ float w2t[NCLS][68];   // transposed W2, padded
    __shared__ float asv[NCLS], adv[NCLS];
    const int tx = threadIdx.x;
    const int node0 = blockIdx.x * TM2;

    for (int f = tx; f < HC1 * NCLS; f += 256) {
        const int k = f / NCLS, c = f - k * NCLS;
        w2t[c][k] = W2[f];
    }
    if (tx < NCLS) {
        asv[tx] = att_src2[tx];
        adv[tx] = att_dst2[tx];
    }
#pragma unroll
    for (int i = 0; i < 8; i++) {
        const int f  = tx + 256 * i;      // 2048 float4 = 128 rows x 16
        const int n  = f >> 4;
        const int k4 = (f & 15) << 2;
        const int gn = node0 + n;
        const float4 v = (gn < N_NODES) ? *(const float4*)(h1e + (size_t)gn * HC1 + k4)
                                        : make_float4(0.f, 0.f, 0.f, 0.f);
        const int ng = n >> 2, ni = n & 3;
        hs[ng][k4 + 0][ni] = v.x;
        hs[ng][k4 + 1][ni] = v.y;
        hs[ng][k4 + 2][ni] = v.z;
        hs[ng][k4 + 3][ni] = v.w;
    }
    __syncthreads();

    const int ng = tx >> 3;          // 0..31 -> nodes ng*4..ng*4+3
    const int cg = tx & 7;           // 0..7  -> classes cg*5..cg*5+4
    const int c0 = cg * 5;

    float acc[4][5];
#pragma unroll
    for (int i = 0; i < 4; i++)
#pragma unroll
        for (int j = 0; j < 5; j++) acc[i][j] = 0.f;

    for (int k = 0; k < HC1; k += 4) {
        float4 hv[4];
#pragma unroll
        for (int t = 0; t < 4; t++) hv[t] = *(const float4*)&hs[ng][k + t][0];
#pragma unroll
        for (int j = 0; j < 5; j++) {
            const float4 wv = *(const float4*)&w2t[c0 + j][k];
            acc[0][j] = fmaf(hv[0].x, wv.x, fmaf(hv[1].x, wv.y, fmaf(hv[2].x, wv.z, fmaf(hv[3].x, wv.w, acc[0][j]))));
            acc[1][j] = fmaf(hv[0].y, wv.x, fmaf(hv[1].y, wv.y, fmaf(hv[2].y, wv.z, fmaf(hv[3].y, wv.w, acc[1][j]))));
            acc[2][j] = fmaf(hv[0].z, wv.x, fmaf(hv[1].z, wv.y, fmaf(hv[2].z, wv.z, fmaf(hv[3].z, wv.w, acc[2][j]))));
            acc[3][j] = fmaf(hv[0].w, wv.x, fmaf(hv[1].w, wv.y, fmaf(hv[2].w, wv.z, fmaf(hv[3].w, wv.w, acc[3][j]))));
        }
    }

    // store h2 + fused att dots (reduce partials over the 8 cg lanes)
    float ps[4], pd[4];
#pragma unroll
    for (int i = 0; i < 4; i++) {
        const int gn = node0 + ng * 4 + i;
        float s = 0.f, d = 0.f;
#pragma unroll
        for (int j = 0; j < 5; j++) {
            s = fmaf(acc[i][j], asv[c0 + j], s);
            d = fmaf(acc[i][j], adv[c0 + j], d);
        }
        ps[i] = s;
        pd[i] = d;
        if (gn < N_NODES) {
#pragma unroll
            for (int j = 0; j < 5; j++)
                h2[(size_t)gn * NCLS + c0 + j] = acc[i][j];
        }
    }
#pragma unroll
    for (int off = 1; off < 8; off <<= 1) {
#pragma unroll
        for (int i = 0; i < 4; i++) {
            ps[i] += __shfl_xor(ps[i], off, 64);
            pd[i] += __shfl_xor(pd[i], off, 64);
        }
    }
    if (cg == 0) {
#pragma unroll
        for (int i = 0; i < 4; i++) {
            const int gn = node0 + ng * 4 + i;
            if (gn < N_NODES) {
                a_src2[gn] = ps[i];
                a_dst2[gn] = pd[i];
            }
        }
    }
}

// ---------------- Layer-2: single-pass online softmax-aggregate + class softmax ----------------
__global__ __launch_bounds__(256) void k_agg2(const float* __restrict__ h2,
                                              const float* __restrict__ a_src,
                                              const float* __restrict__ a_dst,
                                              const int* __restrict__ offs,
                                              const int* __restrict__ srcsort,
                                              const float* __restrict__ b2,
                                              float* __restrict__ out) {
    const int n = blockIdx.x * 4 + (threadIdx.x >> 6);
    if (n >= N_NODES) return;
    const int lane = threadIdx.x & 63;
    const float adn = a_dst[n];
    const int beg = offs[n], end = offs[n + 1];

    float e0 = a_src[n] + adn;
    e0 = e0 > 0.f ? e0 : NEG_SLOPE * e0;
    float m = e0;
    float denom = 1.f;
    float acc = (lane < NCLS) ? h2[(size_t)n * NCLS + lane] : 0.f;

    int j = beg;
    for (; j + 8 <= end; j += 8) {
        int s[8];
#pragma unroll
        for (int t = 0; t < 8; t++) s[t] = srcsort[j + t];
        float q[8], g[8];
#pragma unroll
        for (int t = 0; t < 8; t++) q[t] = a_src[s[t]];
#pragma unroll
        for (int t = 0; t < 8; t++)
            g[t] = (lane < NCLS) ? h2[(size_t)s[t] * NCLS + lane] : 0.f;
        float f[8];
#pragma unroll
        for (int t = 0; t < 8; t++) {
            const float e = q[t] + adn;
            f[t] = e > 0.f ? e : NEG_SLOPE * e;
        }
        const float cm = fmaxf(fmaxf(fmaxf(f[0], f[1]), fmaxf(f[2], f[3])),
                               fmaxf(fmaxf(f[4], f[5]), fmaxf(f[6], f[7])));
        const float nm = fmaxf(m, cm);
        const float sc = __expf(m - nm);
        float w[8];
#pragma unroll
        for (int t = 0; t < 8; t++) w[t] = __expf(f[t] - nm);
        const float wsum = ((w[0] + w[1]) + (w[2] + w[3])) + ((w[4] + w[5]) + (w[6] + w[7]));
        const float wg = fmaf(w[0], g[0], fmaf(w[1], g[1], fmaf(w[2], g[2], fmaf(w[3], g[3],
                         fmaf(w[4], g[4], fmaf(w[5], g[5], fmaf(w[6], g[6], w[7] * g[7])))))));
        denom = fmaf(denom, sc, wsum);
        acc = fmaf(acc, sc, wg);
        m = nm;
    }
    for (; j + 4 <= end; j += 4) {
        const int s0 = srcsort[j], s1 = srcsort[j + 1];
        const int s2 = srcsort[j + 2], s3 = srcsort[j + 3];
        const float q0 = a_src[s0], q1 = a_src[s1];
        const float q2 = a_src[s2], q3 = a_src[s3];
        float g0 = 0.f, g1 = 0.f, g2 = 0.f, g3 = 0.f;
        if (lane < NCLS) {
            g0 = h2[(size_t)s0 * NCLS + lane];
            g1 = h2[(size_t)s1 * NCLS + lane];
            g2 = h2[(size_t)s2 * NCLS + lane];
            g3 = h2[(size_t)s3 * NCLS + lane];
        }
        float f0 = q0 + adn; f0 = f0 > 0.f ? f0 : NEG_SLOPE * f0;
        float f1 = q1 + adn; f1 = f1 > 0.f ? f1 : NEG_SLOPE * f1;
        float f2 = q2 + adn; f2 = f2 > 0.f ? f2 : NEG_SLOPE * f2;
        float f3 = q3 + adn; f3 = f3 > 0.f ? f3 : NEG_SLOPE * f3;
        const float nm = fmaxf(m, fmaxf(fmaxf(f0, f1), fmaxf(f2, f3)));
        const float sc = __expf(m - nm);
        const float w0 = __expf(f0 - nm), w1 = __expf(f1 - nm);
        const float w2 = __expf(f2 - nm), w3 = __expf(f3 - nm);
        denom = fmaf(denom, sc, (w0 + w1) + (w2 + w3));
        acc = fmaf(acc, sc, fmaf(w0, g0, fmaf(w1, g1, fmaf(w2, g2, w3 * g3))));
        m = nm;
    }
    for (; j < end; j++) {
        const int s = srcsort[j];
        float e = a_src[s] + adn;
        e = e > 0.f ? e : NEG_SLOPE * e;
        const float g = (lane < NCLS) ? h2[(size_t)s * NCLS + lane] : 0.f;
        const float nm = fmaxf(m, e);
        const float sc = __expf(m - nm);
        const float w = __expf(e - nm);
        denom = fmaf(denom, sc, w);
        acc = fmaf(acc, sc, w * g);
        m = nm;
    }
    float o = (lane < NCLS) ? (acc / denom + b2[lane]) : -INFINITY;
    float mx = o;
#pragma unroll
    for (int off = 32; off; off >>= 1) mx = fmaxf(mx, __shfl_xor(mx, off, 64));
    const float ex = (lane < NCLS) ? __expf(o - mx) : 0.f;
    float sm = ex;
#pragma unroll
    for (int off = 32; off; off >>= 1) sm += __shfl_xor(sm, off, 64);
    if (lane < NCLS) out[(size_t)n * NCLS + lane] = ex / sm;
}

// ---------------- launcher ----------------
extern "C" void kernel_launch(void* const* d_in, const int* in_sizes, int n_in,
                              void* d_out, int out_size, void* d_ws, size_t ws_size,
                              hipStream_t stream) {
    const float* x   = (const float*)d_in[0];
    const int*   ei  = (const int*)d_in[1];
    const float* W1v = (const float*)d_in[2];
    const float* as1 = (const float*)d_in[3];
    const float* ad1 = (const float*)d_in[4];
    const float* b1  = (const float*)d_in[5];
    const float* W2v = (const float*)d_in[6];
    const float* as2 = (const float*)d_in[7];
    const float* ad2 = (const float*)d_in[8];
    const float* b2  = (const float*)d_in[9];
    const int E = in_sizes[1] / 2;
    const int* esrc = ei;
    const int* edst = ei + E;

    char* wp = (char*)d_ws;
    auto alloc = [&](size_t bytes) {
        char* p = wp;
        wp += (bytes + 255) & ~(size_t)255;
        return p;
    };
    float* h1     = (float*)alloc((size_t)N_NODES * HC1 * 4);
    float* h1e    = (float*)alloc((size_t)N_NODES * HC1 * 4);
    float* a_src1 = (float*)alloc((size_t)N_NODES * H1H * 4);
    float* a_dst1 = (float*)alloc((size_t)N_NODES * H1H * 4);
    float* a_src2 = (float*)alloc((size_t)N_NODES * 4);
    float* a_dst2 = (float*)alloc((size_t)N_NODES * 4);
    int*   offs   = (int*)alloc((size_t)(N_NODES + 1) * 4);
    int*   gbase  = (int*)alloc((size_t)(NBUK + 1) * 4);
    int*   gcur   = (int*)alloc((size_t)NBUK * 4);
    int*   srcsort= (int*)alloc((size_t)E * 4);
    int2*  pairs  = (int2*)alloc((size_t)NBUK * CAP * 8);
    float* h2     = h1;  // h1 dead after k_agg1; reuse for h2

    hipMemsetAsync(gcur, 0, (size_t)NBUK * 4, stream);

    const int NEB = (E + EPB - 1) / EPB;
    k_gemm1<<<(N_NODES + TM - 1) / TM, 256, 0, stream>>>(x, W1v, as1, ad1, h1, a_src1, a_dst1);
    k_bfill<<<NEB, 256, 0, stream>>>(esrc, edst, E, gcur, pairs);
    k_bscan<<<1, 512, 0, stream>>>(gcur, gbase);
    k_bscatter<<<NBUK, 256, 0, stream>>>(pairs, gcur, gbase, offs, srcsort, E);
    k_agg1<<<(N_NODES + 3) / 4, 256, 0, stream>>>(h1, a_src1, a_dst1, offs, srcsort, b1, h1e);
    k_gemm2<<<(N_NODES + TM2 - 1) / TM2, 256, 0, stream>>>(h1e, W2v, as2, ad2, h2, a_src2, a_dst2);
    k_agg2<<<(N_NODES + 3) / 4, 256, 0, stream>>>(h2, a_src2, a_dst2, offs, srcsort, b2, (float*)d_out);
}